// Round 1
// baseline (577.138 us; speedup 1.0000x reference)
//
#include <hip/hip_runtime.h>
#include <stdint.h>
#include <stddef.h>

#define IN_F 4096
#define OUT_F 4096

typedef short s16x8 __attribute__((ext_vector_type(8)));
typedef float f32x4 __attribute__((ext_vector_type(4)));

// ---------- helpers ----------

__device__ static inline unsigned short f2bf(float f) {
    // round-to-nearest-even fp32 -> bf16 (finite inputs)
    uint32_t u = __builtin_bit_cast(uint32_t, f);
    u += 0x7FFFu + ((u >> 16) & 1u);
    return (unsigned short)(u >> 16);
}

__device__ static inline void async16(const void* g, void* l) {
    __builtin_amdgcn_global_load_lds(
        (const __attribute__((address_space(1))) unsigned int*)g,
        (__attribute__((address_space(3))) unsigned int*)l,
        16, 0, 0);
}

__device__ static inline double wred_d(double v) {
#pragma unroll
    for (int o = 32; o > 0; o >>= 1) v += __shfl_down(v, o, 64);
    return v;
}

__device__ static inline int wred_i(int v) {
#pragma unroll
    for (int o = 32; o > 0; o >>= 1) v += __shfl_down(v, o, 64);
    return v;
}

// ---------- K1: per-row delta/alpha (double accumulation) ----------
// one block (256 threads) per input row; row = 16KB, 2nd pass hits L1

__global__ void rowstats_kernel(const float* __restrict__ w,
                                float* __restrict__ alpha_o,
                                double* __restrict__ delta_o) {
    const int row = blockIdx.x;
    const float4* wr = (const float4*)(w + (size_t)row * OUT_F);
    const int t = threadIdx.x;
    const int lane = t & 63, wv = t >> 6;

    double s = 0.0;
#pragma unroll
    for (int it = 0; it < 4; ++it) {
        float4 v = wr[t + it * 256];
        s += (double)fabsf(v.x) + (double)fabsf(v.y) +
             (double)fabsf(v.z) + (double)fabsf(v.w);
    }
    __shared__ double sh_s[4];
    double sw = wred_d(s);
    if (lane == 0) sh_s[wv] = sw;
    __syncthreads();
    const double tot = sh_s[0] + sh_s[1] + sh_s[2] + sh_s[3];
    const double delta = tot * (0.7 / (double)OUT_F);

    double ms = 0.0;
    int cnt = 0;
#pragma unroll
    for (int it = 0; it < 4; ++it) {
        float4 v = wr[t + it * 256];
        double a;
        a = (double)fabsf(v.x); if (a > delta) { ms += a; ++cnt; }
        a = (double)fabsf(v.y); if (a > delta) { ms += a; ++cnt; }
        a = (double)fabsf(v.z); if (a > delta) { ms += a; ++cnt; }
        a = (double)fabsf(v.w); if (a > delta) { ms += a; ++cnt; }
    }
    __shared__ double sh_m[4];
    __shared__ int sh_c[4];
    double msw = wred_d(ms);
    int cw = wred_i(cnt);
    if (lane == 0) { sh_m[wv] = msw; sh_c[wv] = cw; }
    __syncthreads();
    if (t == 0) {
        double mtot = sh_m[0] + sh_m[1] + sh_m[2] + sh_m[3];
        int ctot = sh_c[0] + sh_c[1] + sh_c[2] + sh_c[3];
        alpha_o[row] = (float)(mtot / (double)ctot);
        delta_o[row] = delta;
    }
}

// ---------- K2: ternarize + transpose -> Tt[N=OUT][K=IN] bf16 ----------
// 64x64 tile through LDS so both global read and write are coalesced

__global__ void tern_transpose_kernel(const float* __restrict__ w,
                                      const double* __restrict__ delta,
                                      unsigned short* __restrict__ tt) {
    __shared__ unsigned short lds[64][66];  // +2 pad: conflict-free transpose
    const int t = threadIdx.x;
    const int i0 = blockIdx.y * 64;  // IN dim (rows of w)
    const int j0 = blockIdx.x * 64;  // OUT dim (cols of w)

#pragma unroll 4
    for (int it = 0; it < 16; ++it) {
        int idx = it * 256 + t;
        int r = idx >> 6, c = idx & 63;
        float v = w[(size_t)(i0 + r) * OUT_F + j0 + c];
        double d = delta[i0 + r];
        unsigned short bits = 0;
        if ((double)v > d)       bits = 0x3F80;  // +1.0 bf16
        else if ((double)v < -d) bits = 0xBF80;  // -1.0 bf16
        lds[c][r] = bits;
    }
    __syncthreads();
#pragma unroll 4
    for (int it = 0; it < 16; ++it) {
        int idx = it * 256 + t;
        int r = idx >> 6, c = idx & 63;
        tt[(size_t)(j0 + r) * IN_F + i0 + c] = lds[r][c];
    }
}

// ---------- K3: Xs[b,i] = bf16(x[b,i] * alpha[i]) ----------

__global__ void xscale_kernel(const float* __restrict__ x,
                              const float* __restrict__ alpha,
                              unsigned short* __restrict__ xs) {
    int idx = blockIdx.x * 256 + threadIdx.x;  // one float4 per thread
    float4 v = ((const float4*)x)[idx];
    int col4 = (idx & (IN_F / 4 - 1)) * 4;
    float4 a = *(const float4*)(alpha + col4);
    ushort4 o;
    o.x = f2bf(v.x * a.x);
    o.y = f2bf(v.y * a.y);
    o.z = f2bf(v.z * a.z);
    o.w = f2bf(v.w * a.w);
    ((ushort4*)xs)[idx] = o;
}

// ---------- K4: bf16 MFMA GEMM, m97 structure ----------
// C[M,N] = Xs[M,K] * Tt[N,K]^T + bias ; BM=BN=128, BK=32, 256 thr = 4 waves

__global__ __launch_bounds__(256) void gemm_tern_kernel(
    const unsigned short* __restrict__ Xs,   // [M,K] bf16 bits
    const unsigned short* __restrict__ Tt,   // [N,K] bf16 bits
    const float* __restrict__ bias,
    float* __restrict__ out) {
    __shared__ __align__(16) unsigned short lds_a[128 * 32];  // 8 KB
    __shared__ __align__(16) unsigned short lds_b[128 * 32];  // 8 KB
    const int K = IN_F;
    const int t = threadIdx.x;
    const int lane = t & 63;
    const int wave = t >> 6;
    const int m0 = blockIdx.y * 128;
    const int n0 = blockIdx.x * 128;

    // staging: chunk c covers row r=c>>2, cols (c&3)*8..+8 ; lds offset c*16 B
    const int r0 = t >> 2;
    const int cc = (t & 3) << 3;
    const unsigned short* gA0 = Xs + (size_t)(m0 + r0) * K + cc;
    const unsigned short* gA1 = Xs + (size_t)(m0 + r0 + 64) * K + cc;
    const unsigned short* gB0 = Tt + (size_t)(n0 + r0) * K + cc;
    const unsigned short* gB1 = Tt + (size_t)(n0 + r0 + 64) * K + cc;
    char* lA0 = (char*)lds_a + t * 16;
    char* lA1 = (char*)lds_a + t * 16 + 4096;
    char* lB0 = (char*)lds_b + t * 16;
    char* lB1 = (char*)lds_b + t * 16 + 4096;

    f32x4 acc[4][4];
#pragma unroll
    for (int i = 0; i < 4; ++i)
#pragma unroll
        for (int j = 0; j < 4; ++j)
#pragma unroll
            for (int r = 0; r < 4; ++r) acc[i][j][r] = 0.0f;

    // fragment addressing: A[m=lane&15][k=quad*8+j], B[n=lane&15][k=quad*8+j]
    const int q8 = (lane >> 4) << 3;
    const int lm = lane & 15;
    const int wm = (wave >> 1) << 6;  // wave sub-tile: 2x2 of 64x64
    const int wn = (wave & 1) << 6;
    const unsigned short* pa = lds_a + (wm + lm) * 32 + q8;
    const unsigned short* pb = lds_b + (wn + lm) * 32 + q8;

    for (int k0 = 0; k0 < K; k0 += 32) {
        async16(gA0 + k0, lA0);
        async16(gA1 + k0, lA1);
        async16(gB0 + k0, lB0);
        async16(gB1 + k0, lB1);
        __syncthreads();  // drains vmcnt(0): staging visible in LDS
        s16x8 af[4], bf[4];
#pragma unroll
        for (int i = 0; i < 4; ++i) {
            af[i] = *(const s16x8*)(pa + i * 16 * 32);
            bf[i] = *(const s16x8*)(pb + i * 16 * 32);
        }
#pragma unroll
        for (int i = 0; i < 4; ++i)
#pragma unroll
            for (int j = 0; j < 4; ++j)
                acc[i][j] = __builtin_amdgcn_mfma_f32_16x16x32_bf16(
                    af[i], bf[j], acc[i][j], 0, 0, 0);
        __syncthreads();  // protect LDS before next staging
    }

    // epilogue: C/D layout col=lane&15, row=(lane>>4)*4+reg  [m89/m91]
    const int q4 = (lane >> 4) << 2;
#pragma unroll
    for (int i = 0; i < 4; ++i) {
#pragma unroll
        for (int j = 0; j < 4; ++j) {
            int col = n0 + wn + j * 16 + lm;
            float b = bias[col];
#pragma unroll
            for (int r = 0; r < 4; ++r) {
                int row = m0 + wm + i * 16 + q4 + r;
                out[(size_t)row * OUT_F + col] = acc[i][j][r] + b;
            }
        }
    }
}

// ---------- launch ----------

extern "C" void kernel_launch(void* const* d_in, const int* in_sizes, int n_in,
                              void* d_out, int out_size, void* d_ws, size_t ws_size,
                              hipStream_t stream) {
    const float* x = (const float*)d_in[0];
    const float* w = (const float*)d_in[1];
    const float* bias = (const float*)d_in[2];
    float* out = (float*)d_out;
    const int B = in_sizes[0] / IN_F;  // 8192

    // workspace layout
    char* ws = (char*)d_ws;
    unsigned short* Tt = (unsigned short*)ws;                       // 32 MB  [OUT][IN] bf16
    unsigned short* Xs = (unsigned short*)(ws + (size_t)33554432);  // 64 MB  [B][IN]  bf16
    float* alpha = (float*)(ws + (size_t)33554432 + 67108864);      // 16 KB
    double* delta = (double*)(ws + (size_t)33554432 + 67108864 + 16384);  // 32 KB

    rowstats_kernel<<<IN_F, 256, 0, stream>>>(w, alpha, delta);
    tern_transpose_kernel<<<dim3(OUT_F / 64, IN_F / 64), 256, 0, stream>>>(w, delta, Tt);
    xscale_kernel<<<(B * IN_F / 4) / 256, 256, 0, stream>>>(x, alpha, Xs);
    gemm_tern_kernel<<<dim3(OUT_F / 128, B / 128), 256, 0, stream>>>(Xs, Tt, bias, out);
}

// Round 2
// 565.703 us; speedup vs baseline: 1.0202x; 1.0202x over previous
//
#include <hip/hip_runtime.h>
#include <stdint.h>
#include <stddef.h>

#define IN_F 4096
#define OUT_F 4096

typedef short s16x8 __attribute__((ext_vector_type(8)));
typedef unsigned short u16x8 __attribute__((ext_vector_type(8)));
typedef float f32x4 __attribute__((ext_vector_type(4)));

// ---------- helpers ----------

__device__ static inline unsigned short f2bf(float f) {
    // round-to-nearest-even fp32 -> bf16 (finite inputs)
    uint32_t u = __builtin_bit_cast(uint32_t, f);
    u += 0x7FFFu + ((u >> 16) & 1u);
    return (unsigned short)(u >> 16);
}

__device__ static inline void async16(const void* g, void* l) {
    __builtin_amdgcn_global_load_lds(
        (const __attribute__((address_space(1))) unsigned int*)g,
        (__attribute__((address_space(3))) unsigned int*)l,
        16, 0, 0);
}

__device__ static inline double wred_d(double v) {
#pragma unroll
    for (int o = 32; o > 0; o >>= 1) v += __shfl_down(v, o, 64);
    return v;
}

__device__ static inline int wred_i(int v) {
#pragma unroll
    for (int o = 32; o > 0; o >>= 1) v += __shfl_down(v, o, 64);
    return v;
}

// ---------- K1: fused per-row stats + ternarize ----------
// one block (256 thr) per input row; row cached in LDS (single HBM read of w)
// writes alpha[i] (float) and T[i][j] = bf16 ternary, NON-transposed, coalesced

__global__ __launch_bounds__(256) void rowstats_tern_kernel(
    const float* __restrict__ w,
    float* __restrict__ alpha_o,
    unsigned short* __restrict__ T) {
    __shared__ float rowbuf[OUT_F];          // 16 KB
    __shared__ double sh_s[4], sh_m[4];
    __shared__ int sh_c[4];
    const int row = blockIdx.x;
    const int t = threadIdx.x;
    const int lane = t & 63, wv = t >> 6;
    const float4* wr = (const float4*)(w + (size_t)row * OUT_F);

    // pass 1: load row -> LDS, accumulate sum|w| in double
    double s = 0.0;
#pragma unroll
    for (int it = 0; it < 4; ++it) {
        float4 v = wr[t + it * 256];
        ((float4*)rowbuf)[t + it * 256] = v;
        s += (double)fabsf(v.x) + (double)fabsf(v.y) +
             (double)fabsf(v.z) + (double)fabsf(v.w);
    }
    double sw = wred_d(s);
    if (lane == 0) sh_s[wv] = sw;
    __syncthreads();  // rowbuf + sh_s ready
    const double delta = (sh_s[0] + sh_s[1] + sh_s[2] + sh_s[3]) *
                         (0.7 / (double)OUT_F);

    // pass 2 from LDS (conflict-free k*256+t layout): masked sum/count,
    // and ternarize+store in the same sweep (block-coalesced u16 stores)
    unsigned short* trow = T + (size_t)row * OUT_F;
    double ms = 0.0;
    int cnt = 0;
#pragma unroll
    for (int k = 0; k < 16; ++k) {
        float v = rowbuf[k * 256 + t];
        double a = (double)fabsf(v);
        if (a > delta) { ms += a; ++cnt; }
        unsigned short bits = 0;
        if ((double)v > delta)       bits = 0x3F80;  // +1.0 bf16
        else if ((double)v < -delta) bits = 0xBF80;  // -1.0 bf16
        trow[k * 256 + t] = bits;
    }
    double msw = wred_d(ms);
    int cw = wred_i(cnt);
    if (lane == 0) { sh_m[wv] = msw; sh_c[wv] = cw; }
    __syncthreads();
    if (t == 0) {
        double mtot = sh_m[0] + sh_m[1] + sh_m[2] + sh_m[3];
        int ctot = sh_c[0] + sh_c[1] + sh_c[2] + sh_c[3];
        alpha_o[row] = (float)(mtot / (double)ctot);
    }
}

// ---------- K2: bf16 transpose T[IN][OUT] -> Tt[OUT][IN] ----------
// 64x64 tile, 16B vector global reads and writes, LDS element transpose

__global__ __launch_bounds__(256) void transpose_bf16_kernel(
    const unsigned short* __restrict__ T,
    unsigned short* __restrict__ Tt) {
    __shared__ unsigned short lds[64][68];  // pad 68: 8B-aligned rows, spread banks
    const int t = threadIdx.x;
    const int i0 = blockIdx.y * 64;  // IN
    const int j0 = blockIdx.x * 64;  // OUT

#pragma unroll
    for (int it = 0; it < 2; ++it) {
        int idx = it * 256 + t;
        int r = idx >> 3;          // row within tile (IN dim)
        int c8 = idx & 7;          // 8-short chunk within row (OUT dim)
        u16x8 v = *(const u16x8*)(T + (size_t)(i0 + r) * OUT_F + j0 + c8 * 8);
#pragma unroll
        for (int k = 0; k < 8; ++k) lds[c8 * 8 + k][r] = v[k];
    }
    __syncthreads();
#pragma unroll
    for (int it = 0; it < 2; ++it) {
        int idx = it * 256 + t;
        int rr = idx >> 3;         // row within Tt tile (OUT dim)
        int cc = idx & 7;          // 8-short chunk (IN dim)
        // two aligned 8B reads (row stride 136 B keeps 8B alignment)
        unsigned long long lo = *(const unsigned long long*)&lds[rr][cc * 8];
        unsigned long long hi = *(const unsigned long long*)&lds[rr][cc * 8 + 4];
        unsigned long long* dst =
            (unsigned long long*)(Tt + (size_t)(j0 + rr) * IN_F + i0 + cc * 8);
        dst[0] = lo;
        dst[1] = hi;
    }
}

// ---------- K3: Xs[b,i] = bf16(x[b,i] * alpha[i]), 8 elems/thread ----------

__global__ __launch_bounds__(256) void xscale_kernel(
    const float* __restrict__ x,
    const float* __restrict__ alpha,
    unsigned short* __restrict__ xs) {
    int idx = blockIdx.x * 256 + threadIdx.x;  // 8 floats per thread
    const float4* x4 = (const float4*)x;
    float4 v0 = x4[2 * idx];
    float4 v1 = x4[2 * idx + 1];
    int col = (idx & (IN_F / 8 - 1)) * 8;
    float4 a0 = *(const float4*)(alpha + col);
    float4 a1 = *(const float4*)(alpha + col + 4);
    u16x8 o;
    o[0] = f2bf(v0.x * a0.x);
    o[1] = f2bf(v0.y * a0.y);
    o[2] = f2bf(v0.z * a0.z);
    o[3] = f2bf(v0.w * a0.w);
    o[4] = f2bf(v1.x * a1.x);
    o[5] = f2bf(v1.y * a1.y);
    o[6] = f2bf(v1.z * a1.z);
    o[7] = f2bf(v1.w * a1.w);
    ((u16x8*)xs)[idx] = o;
}

// ---------- K4: bf16 MFMA GEMM, m97 structure (unchanged, known-good) ----------
// C[M,N] = Xs[M,K] * Tt[N,K]^T + bias ; BM=BN=128, BK=32, 256 thr = 4 waves

__global__ __launch_bounds__(256) void gemm_tern_kernel(
    const unsigned short* __restrict__ Xs,   // [M,K] bf16 bits
    const unsigned short* __restrict__ Tt,   // [N,K] bf16 bits
    const float* __restrict__ bias,
    float* __restrict__ out) {
    __shared__ __align__(16) unsigned short lds_a[128 * 32];  // 8 KB
    __shared__ __align__(16) unsigned short lds_b[128 * 32];  // 8 KB
    const int K = IN_F;
    const int t = threadIdx.x;
    const int lane = t & 63;
    const int wave = t >> 6;
    const int m0 = blockIdx.y * 128;
    const int n0 = blockIdx.x * 128;

    const int r0 = t >> 2;
    const int cc = (t & 3) << 3;
    const unsigned short* gA0 = Xs + (size_t)(m0 + r0) * K + cc;
    const unsigned short* gA1 = Xs + (size_t)(m0 + r0 + 64) * K + cc;
    const unsigned short* gB0 = Tt + (size_t)(n0 + r0) * K + cc;
    const unsigned short* gB1 = Tt + (size_t)(n0 + r0 + 64) * K + cc;
    char* lA0 = (char*)lds_a + t * 16;
    char* lA1 = (char*)lds_a + t * 16 + 4096;
    char* lB0 = (char*)lds_b + t * 16;
    char* lB1 = (char*)lds_b + t * 16 + 4096;

    f32x4 acc[4][4];
#pragma unroll
    for (int i = 0; i < 4; ++i)
#pragma unroll
        for (int j = 0; j < 4; ++j)
#pragma unroll
            for (int r = 0; r < 4; ++r) acc[i][j][r] = 0.0f;

    const int q8 = (lane >> 4) << 3;
    const int lm = lane & 15;
    const int wm = (wave >> 1) << 6;
    const int wn = (wave & 1) << 6;
    const unsigned short* pa = lds_a + (wm + lm) * 32 + q8;
    const unsigned short* pb = lds_b + (wn + lm) * 32 + q8;

    for (int k0 = 0; k0 < K; k0 += 32) {
        async16(gA0 + k0, lA0);
        async16(gA1 + k0, lA1);
        async16(gB0 + k0, lB0);
        async16(gB1 + k0, lB1);
        __syncthreads();
        s16x8 af[4], bf[4];
#pragma unroll
        for (int i = 0; i < 4; ++i) {
            af[i] = *(const s16x8*)(pa + i * 16 * 32);
            bf[i] = *(const s16x8*)(pb + i * 16 * 32);
        }
#pragma unroll
        for (int i = 0; i < 4; ++i)
#pragma unroll
            for (int j = 0; j < 4; ++j)
                acc[i][j] = __builtin_amdgcn_mfma_f32_16x16x32_bf16(
                    af[i], bf[j], acc[i][j], 0, 0, 0);
        __syncthreads();
    }

    const int q4 = (lane >> 4) << 2;
#pragma unroll
    for (int i = 0; i < 4; ++i) {
#pragma unroll
        for (int j = 0; j < 4; ++j) {
            int col = n0 + wn + j * 16 + lm;
            float b = bias[col];
#pragma unroll
            for (int r = 0; r < 4; ++r) {
                int row = m0 + wm + i * 16 + q4 + r;
                out[(size_t)row * OUT_F + col] = acc[i][j][r] + b;
            }
        }
    }
}

// ---------- launch ----------

extern "C" void kernel_launch(void* const* d_in, const int* in_sizes, int n_in,
                              void* d_out, int out_size, void* d_ws, size_t ws_size,
                              hipStream_t stream) {
    const float* x = (const float*)d_in[0];
    const float* w = (const float*)d_in[1];
    const float* bias = (const float*)d_in[2];
    float* out = (float*)d_out;
    const int B = in_sizes[0] / IN_F;  // 8192

    // ws layout (96 MB + 16 KB):
    //   [0, 32M)   Tt [OUT][IN] bf16
    //   [32M, 96M) Xs [B][IN] bf16 ; T [IN][OUT] bf16 lives in [32M, 64M)
    //              (T is dead after K2; K3 overwrites it — stream-serial safe)
    //   [96M, ..)  alpha fp32
    char* ws = (char*)d_ws;
    unsigned short* Tt = (unsigned short*)ws;
    unsigned short* T = (unsigned short*)(ws + (size_t)33554432);
    unsigned short* Xs = (unsigned short*)(ws + (size_t)33554432);
    float* alpha = (float*)(ws + (size_t)100663296);

    rowstats_tern_kernel<<<IN_F, 256, 0, stream>>>(w, alpha, T);
    transpose_bf16_kernel<<<dim3(OUT_F / 64, IN_F / 64), 256, 0, stream>>>(T, Tt);
    xscale_kernel<<<(B * IN_F / 8) / 256, 256, 0, stream>>>(x, alpha, Xs);
    gemm_tern_kernel<<<dim3(OUT_F / 128, B / 128), 256, 0, stream>>>(Xs, Tt, bias, out);
}

// Round 3
// 444.312 us; speedup vs baseline: 1.2989x; 1.2732x over previous
//
#include <hip/hip_runtime.h>
#include <stdint.h>
#include <stddef.h>

#define IN_F 4096
#define OUT_F 4096

typedef int i32x4 __attribute__((ext_vector_type(4)));
typedef float f32x4 __attribute__((ext_vector_type(4)));

// ---------- helpers ----------

__device__ static inline void async16(const void* g, void* l) {
    __builtin_amdgcn_global_load_lds(
        (const __attribute__((address_space(1))) unsigned int*)g,
        (__attribute__((address_space(3))) unsigned int*)l,
        16, 0, 0);
}

__device__ static inline double wred_d(double v) {
#pragma unroll
    for (int o = 32; o > 0; o >>= 1) v += __shfl_down(v, o, 64);
    return v;
}

__device__ static inline int wred_i(int v) {
#pragma unroll
    for (int o = 32; o > 0; o >>= 1) v += __shfl_down(v, o, 64);
    return v;
}

__device__ static inline float wred_max(float v) {
#pragma unroll
    for (int o = 32; o > 0; o >>= 1) v = fmaxf(v, __shfl_down(v, o, 64));
    return v;
}

// ---------- K1: fused per-row stats + ternarize -> T i8 {-1,0,1} ----------
// one block (256 thr) per input row; row cached in LDS (single HBM read of w)

__global__ __launch_bounds__(256) void rowstats_tern_kernel(
    const float* __restrict__ w,
    float* __restrict__ alpha_o,
    int8_t* __restrict__ T) {
    __shared__ float rowbuf[OUT_F];          // 16 KB
    __shared__ double sh_s[4], sh_m[4];
    __shared__ int sh_c[4];
    const int row = blockIdx.x;
    const int t = threadIdx.x;
    const int lane = t & 63, wv = t >> 6;
    const float4* wr = (const float4*)(w + (size_t)row * OUT_F);

    // pass 1: load row -> LDS, accumulate sum|w| in double
    double s = 0.0;
#pragma unroll
    for (int it = 0; it < 4; ++it) {
        float4 v = wr[t + it * 256];
        ((float4*)rowbuf)[t + it * 256] = v;
        s += (double)fabsf(v.x) + (double)fabsf(v.y) +
             (double)fabsf(v.z) + (double)fabsf(v.w);
    }
    double sw = wred_d(s);
    if (lane == 0) sh_s[wv] = sw;
    __syncthreads();
    const double delta = (sh_s[0] + sh_s[1] + sh_s[2] + sh_s[3]) *
                         (0.7 / (double)OUT_F);

    // pass 2 from LDS: masked sum/count + ternarize + coalesced i8 stores
    int8_t* trow = T + (size_t)row * OUT_F;
    double ms = 0.0;
    int cnt = 0;
#pragma unroll
    for (int k = 0; k < 16; ++k) {
        float v = rowbuf[k * 256 + t];
        double a = (double)fabsf(v);
        if (a > delta) { ms += a; ++cnt; }
        int8_t q = 0;
        if ((double)v > delta)       q = 1;
        else if ((double)v < -delta) q = -1;
        trow[k * 256 + t] = q;
    }
    double msw = wred_d(ms);
    int cw = wred_i(cnt);
    if (lane == 0) { sh_m[wv] = msw; sh_c[wv] = cw; }
    __syncthreads();
    if (t == 0) {
        double mtot = sh_m[0] + sh_m[1] + sh_m[2] + sh_m[3];
        int ctot = sh_c[0] + sh_c[1] + sh_c[2] + sh_c[3];
        alpha_o[row] = (float)(mtot / (double)ctot);
    }
}

// ---------- K2: i8 transpose T[IN][OUT] -> Tt[OUT][IN] ----------
// 64x64 byte tile via LDS; 4B reads, 8B writes, both coalesced

__global__ __launch_bounds__(256) void transpose_i8_kernel(
    const int8_t* __restrict__ T,
    int8_t* __restrict__ Tt) {
    __shared__ int8_t lds[64][72];  // 72: 8B-aligned rows, spreads banks
    const int t = threadIdx.x;
    const int i0 = blockIdx.y * 64;  // IN
    const int j0 = blockIdx.x * 64;  // OUT

#pragma unroll
    for (int it = 0; it < 4; ++it) {
        int idx = it * 256 + t;
        int r = idx >> 4;          // row (IN dim)
        int c4 = idx & 15;         // 4-byte chunk (OUT dim)
        uchar4 v = *(const uchar4*)(T + (size_t)(i0 + r) * OUT_F + j0 + c4 * 4);
        lds[c4 * 4 + 0][r] = (int8_t)v.x;
        lds[c4 * 4 + 1][r] = (int8_t)v.y;
        lds[c4 * 4 + 2][r] = (int8_t)v.z;
        lds[c4 * 4 + 3][r] = (int8_t)v.w;
    }
    __syncthreads();
#pragma unroll
    for (int it = 0; it < 2; ++it) {
        int idx = it * 256 + t;
        int rr = idx >> 3;         // row (OUT dim)
        int cc = idx & 7;          // 8-byte chunk (IN dim)
        unsigned long long v = *(const unsigned long long*)&lds[rr][cc * 8];
        *(unsigned long long*)(Tt + (size_t)(j0 + rr) * IN_F + i0 + cc * 8) = v;
    }
}

// ---------- K3: per-batch-row quantize Xq = rint(x*alpha * 127/rowmax) ----------

__global__ __launch_bounds__(256) void xquant_kernel(
    const float* __restrict__ x,
    const float* __restrict__ alpha,
    int8_t* __restrict__ xq,
    float* __restrict__ scale_o) {
    __shared__ float rowbuf[IN_F];   // xs values, 16 KB
    __shared__ float sh_mx[4];
    const int row = blockIdx.x;
    const int t = threadIdx.x;
    const int lane = t & 63, wv = t >> 6;
    const float4* xr = (const float4*)(x + (size_t)row * IN_F);
    const float4* ar = (const float4*)alpha;

    float mx = 0.0f;
#pragma unroll
    for (int it = 0; it < 4; ++it) {
        float4 v = xr[t + it * 256];
        float4 a = ar[t + it * 256];
        v.x *= a.x; v.y *= a.y; v.z *= a.z; v.w *= a.w;
        ((float4*)rowbuf)[t + it * 256] = v;
        mx = fmaxf(mx, fmaxf(fmaxf(fabsf(v.x), fabsf(v.y)),
                             fmaxf(fabsf(v.z), fabsf(v.w))));
    }
    float mw = wred_max(mx);
    if (lane == 0) sh_mx[wv] = mw;
    __syncthreads();
    const float rmax = fmaxf(fmaxf(sh_mx[0], sh_mx[1]), fmaxf(sh_mx[2], sh_mx[3]));
    const float inv = (rmax > 0.0f) ? (127.0f / rmax) : 0.0f;

    int8_t* qrow = xq + (size_t)row * IN_F;
#pragma unroll
    for (int k = 0; k < 16; ++k) {
        float v = rowbuf[k * 256 + t];
        qrow[k * 256 + t] = (int8_t)__float2int_rn(v * inv);
    }
    if (t == 0) scale_o[row] = (rmax > 0.0f) ? (rmax / 127.0f) : 1.0f;
}

// ---------- K4: i8 MFMA GEMM, m97 structure, BK=64 ----------
// acc[M,N] = Xq[M,K] * Tq[N,K]^T (exact i32); out = scale[m]*acc + bias[n]

__global__ __launch_bounds__(256) void gemm_i8_kernel(
    const int8_t* __restrict__ Xq,   // [M,K]
    const int8_t* __restrict__ Tq,   // [N,K]
    const float* __restrict__ scale, // [M]
    const float* __restrict__ bias,  // [N]
    float* __restrict__ out) {
    __shared__ __align__(16) int8_t lds_a[128 * 64];  // 8 KB
    __shared__ __align__(16) int8_t lds_b[128 * 64];  // 8 KB
    const int K = IN_F;
    const int t = threadIdx.x;
    const int lane = t & 63;
    const int wave = t >> 6;
    const int m0 = blockIdx.y * 128;
    const int n0 = blockIdx.x * 128;

    // staging: thread t -> row r0 = t>>2, byte chunk (t&3)*16 of the 64B row
    const int r0 = t >> 2;
    const int cb = (t & 3) << 4;
    const int8_t* gA0 = Xq + (size_t)(m0 + r0) * K + cb;
    const int8_t* gA1 = Xq + (size_t)(m0 + r0 + 64) * K + cb;
    const int8_t* gB0 = Tq + (size_t)(n0 + r0) * K + cb;
    const int8_t* gB1 = Tq + (size_t)(n0 + r0 + 64) * K + cb;
    char* lA0 = (char*)lds_a + t * 16;
    char* lA1 = (char*)lds_a + t * 16 + 4096;
    char* lB0 = (char*)lds_b + t * 16;
    char* lB1 = (char*)lds_b + t * 16 + 4096;

    i32x4 acc[4][4];
#pragma unroll
    for (int i = 0; i < 4; ++i)
#pragma unroll
        for (int j = 0; j < 4; ++j)
#pragma unroll
            for (int r = 0; r < 4; ++r) acc[i][j][r] = 0;

    // fragments: lane holds 16 consecutive i8 along K at k = (lane>>4)*16
    const int q16 = (lane >> 4) << 4;
    const int lm = lane & 15;
    const int wm = (wave >> 1) << 6;
    const int wn = (wave & 1) << 6;
    const int8_t* pa = lds_a + (wm + lm) * 64 + q16;
    const int8_t* pb = lds_b + (wn + lm) * 64 + q16;

    for (int k0 = 0; k0 < K; k0 += 64) {
        async16(gA0 + k0, lA0);
        async16(gA1 + k0, lA1);
        async16(gB0 + k0, lB0);
        async16(gB1 + k0, lB1);
        __syncthreads();  // drains vmcnt(0): staging visible in LDS
        i32x4 af[4], bf[4];
#pragma unroll
        for (int i = 0; i < 4; ++i) {
            af[i] = *(const i32x4*)(pa + i * 16 * 64);
            bf[i] = *(const i32x4*)(pb + i * 16 * 64);
        }
#pragma unroll
        for (int i = 0; i < 4; ++i)
#pragma unroll
            for (int j = 0; j < 4; ++j)
                acc[i][j] = __builtin_amdgcn_mfma_i32_16x16x64_i8(
                    af[i], bf[j], acc[i][j], 0, 0, 0);
        __syncthreads();  // protect LDS before next staging
    }

    // epilogue: C/D layout col=lane&15, row=(lane>>4)*4+reg (dtype-independent)
    const int q4 = (lane >> 4) << 2;
#pragma unroll
    for (int i = 0; i < 4; ++i) {
        float sc[4];
#pragma unroll
        for (int r = 0; r < 4; ++r) sc[r] = scale[m0 + wm + i * 16 + q4 + r];
#pragma unroll
        for (int j = 0; j < 4; ++j) {
            int col = n0 + wn + j * 16 + lm;
            float b = bias[col];
#pragma unroll
            for (int r = 0; r < 4; ++r) {
                int row = m0 + wm + i * 16 + q4 + r;
                out[(size_t)row * OUT_F + col] =
                    (float)acc[i][j][r] * sc[r] + b;
            }
        }
    }
}

// ---------- launch ----------

extern "C" void kernel_launch(void* const* d_in, const int* in_sizes, int n_in,
                              void* d_out, int out_size, void* d_ws, size_t ws_size,
                              hipStream_t stream) {
    const float* x = (const float*)d_in[0];
    const float* w = (const float*)d_in[1];
    const float* bias = (const float*)d_in[2];
    float* out = (float*)d_out;
    const int B = in_sizes[0] / IN_F;  // 8192

    // ws layout (48 MB + 48 KB):
    //   [0, 16M)    Tt [OUT][IN] i8 (transposed ternary)
    //   [16M, 32M)  T  [IN][OUT] i8 (temp; dead after K2)
    //   [16M, 48M)  Xq [B][IN] i8 (K3 overwrites T — stream-serial safe)
    //   [48M, ..)   alpha fp32[IN], scale fp32[B]
    char* ws = (char*)d_ws;
    int8_t* Tt = (int8_t*)ws;
    int8_t* T = (int8_t*)(ws + (size_t)16777216);
    int8_t* Xq = (int8_t*)(ws + (size_t)16777216);
    float* alpha = (float*)(ws + (size_t)50331648);
    float* scale = (float*)(ws + (size_t)50331648 + 16384);

    rowstats_tern_kernel<<<IN_F, 256, 0, stream>>>(w, alpha, T);
    transpose_i8_kernel<<<dim3(OUT_F / 64, IN_F / 64), 256, 0, stream>>>(T, Tt);
    xquant_kernel<<<B, 256, 0, stream>>>(x, alpha, Xq, scale);
    gemm_i8_kernel<<<dim3(OUT_F / 128, B / 128), 256, 0, stream>>>(Xq, Tt, scale, bias, out);
}